// Round 16
// baseline (489.631 us; speedup 1.0000x reference)
//
#include <hip/hip_runtime.h>
#include <hip/hip_bf16.h>

#define HALF_ROWS 262144
#define TAU 0.04f
#define BT_OFF 1024
#define LIST_OFF 328704              // BT_OFF + 320*512*2
#define PART_OFF 16777216            // partials: 2 x 262144 x 32B
#define CAP 262144
#define NC 16

typedef __attribute__((ext_vector_type(8))) short s16x8;
typedef __attribute__((ext_vector_type(4))) float f32x4;
typedef __attribute__((ext_vector_type(16))) float f32x16;

__device__ __forceinline__ unsigned short f2bf(float f) {
  union { float f; unsigned u; } v; v.f = f;
  unsigned r = v.u + 0x7fffu + ((v.u >> 16) & 1u);   // RTNE
  return (unsigned short)(r >> 16);
}

#define GLOAD_LDS16(g, p) \
  __builtin_amdgcn_global_load_lds((const __attribute__((address_space(1))) void*)(g), \
                                   (__attribute__((address_space(3))) void*)(p), 16, 0, 0)

__device__ __forceinline__ s16x8 cvt8(const f32x4& a, const f32x4& b) {
  union { int i[4]; s16x8 v; } u;
  asm("v_cvt_pk_bf16_f32 %0, %1, %2" : "=v"(u.i[0]) : "v"(a[0]), "v"(a[1]));
  asm("v_cvt_pk_bf16_f32 %0, %1, %2" : "=v"(u.i[1]) : "v"(a[2]), "v"(a[3]));
  asm("v_cvt_pk_bf16_f32 %0, %1, %2" : "=v"(u.i[2]) : "v"(b[0]), "v"(b[1]));
  asm("v_cvt_pk_bf16_f32 %0, %1, %2" : "=v"(u.i[3]) : "v"(b[2]), "v"(b[3]));
  return u.v;
}

// ---- prep: W1 -> Bf in 32x32x16 B-fragment order [cb10][kst32][lane64][8] ----
// col = cb*32 + (l&31); k = kst*16 + (l>>5)*8 + j
__global__ void moe_prep(const float* __restrict__ gw1, const float* __restrict__ aw1,
                         const float* __restrict__ bw1, unsigned short* __restrict__ Bf,
                         unsigned* __restrict__ cnt) {
  if (blockIdx.x == 0 && threadIdx.x == 0) *cnt = 0u;
  int idx = blockIdx.x * 512 + threadIdx.x;          // 163840
  int j = idx & 7, l = (idx >> 3) & 63, kst = (idx >> 9) & 31, cb = idx >> 14;
  int col = cb * 32 + (l & 31);
  int k = kst * 16 + ((l >> 5) << 3) + j;
  float v;
  if (col < 64)       v = gw1[k * 64 + col];
  else if (col < 192) v = aw1[k * 128 + (col - 64)];
  else                v = bw1[k * 128 + (col - 192)];
  Bf[idx] = f2bf(v);
}

// ---- main: R13 producer/consumer skeleton, 32x32x16 fragments ----------------
// 4 producers (A reg-staged 2-deep + B DMA 3-ring, vmcnt(9) steady, 16 bars);
// 8 consumers = 4 row-groups(32) x 2 col-halves(160): 12 ds_reads + 10 MFMA
// per chunk (was 21+20). Partials -> ws; combine gates.
__global__ __launch_bounds__(768, 3) void moe_main(
    const float* __restrict__ x, const unsigned short* __restrict__ Bf,
    const float* __restrict__ gb1, const float* __restrict__ gw2,
    const float* __restrict__ ab1, const float* __restrict__ aw2,
    const float* __restrict__ bb1, const float* __restrict__ bw2,
    float* __restrict__ part) {
  __shared__ char Asl[2][8192];               // [grp4*ks2][lane64][16B]
  __shared__ char Bsl[3][20480];              // [seg20][lane64][16B]

  const int tid = threadIdx.x;
  const int w = tid >> 6, l = tid & 63;
  const long br = (long)blockIdx.x * 128;

  if (w < 4) {
    // ======================= PRODUCER (R13 ledger, 32-row frags) ==============
    const float* apg = x + (br + w * 32 + (l & 31)) * 256 + ((l >> 5) << 3);
    const unsigned short* bsrc = Bf + l * 8;
    const int s0 = w * 5;                     // 5 B-segments per producer

    f32x4 sA[4], sB[4];
#define ISSUE_A(KC, S)                                                             \
    {                                                                              \
      const float* pb = ((KC) < 8) ? apg : (apg + (long)HALF_ROWS * 256);          \
      const float* p0 = pb + ((KC) & 7) * 32;                                      \
      asm volatile("global_load_dwordx4 %0, %1, off" : "=&v"(S[0]) : "v"(p0));     \
      asm volatile("global_load_dwordx4 %0, %1, off" : "=&v"(S[1]) : "v"(p0 + 4)); \
      asm volatile("global_load_dwordx4 %0, %1, off" : "=&v"(S[2]) : "v"(p0 + 16));\
      asm volatile("global_load_dwordx4 %0, %1, off" : "=&v"(S[3]) : "v"(p0 + 20));\
    }
    auto issueB = [&](int kc) {
      char* dst = Bsl[((unsigned)kc) % 3u] + s0 * 1024;
#pragma unroll
      for (int i = 0; i < 5; ++i) {
        int s = s0 + i;                       // seg = cb*2+ks
        GLOAD_LDS16(bsrc + (((size_t)((s >> 1) * 32 + kc * 2 + (s & 1))) << 9),
                    dst + i * 1024);
      }
    };
#define COMMIT_A(KC, S)                                                            \
    {                                                                              \
      char* dst = Asl[(KC) & 1];                                                   \
      s16x8 v0 = cvt8(S[0], S[1]);                                                 \
      s16x8 v1 = cvt8(S[2], S[3]);                                                 \
      *(s16x8*)(dst + ((w * 2) * 64 + l) * 16) = v0;                               \
      *(s16x8*)(dst + ((w * 2 + 1) * 64 + l) * 16) = v1;                           \
    }
#define PWAIT(N) asm volatile("s_waitcnt vmcnt(" #N ")" ::: "memory"); \
                 __builtin_amdgcn_sched_barrier(0)
#define PBAR()   asm volatile("s_waitcnt lgkmcnt(0)" ::: "memory");    \
                 __builtin_amdgcn_s_barrier()

    ISSUE_A(0, sA) issueB(0);
    ISSUE_A(1, sB) issueB(1);
    PWAIT(9);
    COMMIT_A(0, sA)
    PBAR();                                   // barrier #1

#pragma unroll 1
    for (int kc = 0; kc < 14; kc += 2) {
      ISSUE_A(kc + 2, sA) issueB(kc + 2);
      PWAIT(9);
      COMMIT_A(kc + 1, sB)
      PBAR();
      if (kc + 3 < NC) {
        ISSUE_A(kc + 3, sB) issueB(kc + 3);
        PWAIT(9);
      } else {
        PWAIT(0);
      }
      COMMIT_A(kc + 2, sA)
      PBAR();
    }
    PWAIT(0);
    COMMIT_A(15, sB)
    PBAR();                                   // barrier #16
  } else {
    // ======================= CONSUMER =========================================
    const int c = w - 4;                      // 0..7
    const int ch = c >> 2, g = c & 3;         // col-half, row-group (32 rows)
    const int lo32 = l & 31, hi2 = l >> 5;

    f32x16 acc[5];
#pragma unroll
    for (int t = 0; t < 5; ++t)
#pragma unroll
      for (int q = 0; q < 16; ++q) acc[t][q] = 0.f;

#pragma unroll 1
    for (int kc = 0; kc < NC; ++kc) {
      __builtin_amdgcn_s_barrier();
      asm volatile("" ::: "memory");
      const char* ab = Asl[kc & 1];
      const char* bb = Bsl[((unsigned)kc) % 3u];
      s16x8 a0 = *(const s16x8*)(ab + ((g * 2) * 64 + l) * 16);
      s16x8 a1 = *(const s16x8*)(ab + ((g * 2 + 1) * 64 + l) * 16);
#pragma unroll
      for (int t = 0; t < 5; ++t) {
        int seg = (ch * 5 + t) * 2;
        s16x8 b0 = *(const s16x8*)(bb + (seg * 64 + l) * 16);
        s16x8 b1f = *(const s16x8*)(bb + ((seg + 1) * 64 + l) * 16);
        acc[t] = __builtin_amdgcn_mfma_f32_32x32x16_bf16(a0, b0, acc[t], 0, 0, 0);
        acc[t] = __builtin_amdgcn_mfma_f32_32x32x16_bf16(a1, b1f, acc[t], 0, 0, 0);
      }
    }

    // ---- epilogue: bias+relu+heads; reduce over 32 cols per tile -------------
    float pg0[16], pg1[16], pa0[16], pa1[16], pq0[16], pq1[16];
#pragma unroll
    for (int q = 0; q < 16; ++q) {
      pg0[q] = pg1[q] = pa0[q] = pa1[q] = pq0[q] = pq1[q] = 0.f;
    }
#pragma unroll
    for (int t = 0; t < 5; ++t) {
      int col = ch * 160 + t * 32 + lo32;
      int c0 = ch * 160 + t * 32;
      float b1, w0, w1;
      if (c0 < 64)       { b1 = gb1[col];        w0 = gw2[col * 2];        w1 = gw2[col * 2 + 1]; }
      else if (c0 < 192) { int cc = col - 64;  b1 = ab1[cc]; w0 = aw2[cc * 2]; w1 = aw2[cc * 2 + 1]; }
      else               { int cc = col - 192; b1 = bb1[cc]; w0 = bw2[cc * 2]; w1 = bw2[cc * 2 + 1]; }
#pragma unroll
      for (int q = 0; q < 16; ++q) {
        float h = fmaxf(acc[t][q] + b1, 0.f);
        float t0 = h * w0, t1 = h * w1;
        if (c0 < 64)       { pg0[q] += t0; pg1[q] += t1; }
        else if (c0 < 192) { pa0[q] += t0; pa1[q] += t1; }
        else               { pq0[q] += t0; pq1[q] += t1; }
      }
    }
#pragma unroll
    for (int m = 1; m < 32; m <<= 1)
#pragma unroll
      for (int q = 0; q < 16; ++q) {
        pg0[q] += __shfl_xor(pg0[q], m); pg1[q] += __shfl_xor(pg1[q], m);
        pa0[q] += __shfl_xor(pa0[q], m); pa1[q] += __shfl_xor(pa1[q], m);
        pq0[q] += __shfl_xor(pq0[q], m); pq1[q] += __shfl_xor(pq1[q], m);
      }
    if (lo32 == 0) {
#pragma unroll
      for (int q = 0; q < 16; ++q) {
        long row = br + g * 32 + (q & 3) + 8 * (q >> 2) + 4 * hi2;
        float* pp = part + ((long)ch * 262144 + row) * 8;
        pp[0] = pg0[q]; pp[1] = pg1[q]; pp[2] = pa0[q];
        pp[3] = pa1[q]; pp[4] = pq0[q]; pp[5] = pq1[q];
      }
    }
  }
}

// ---- combine: merge halves, gate, write out, queue TAU fixup list ------------
__global__ void moe_combine(const float* __restrict__ part,
                            const float* __restrict__ gb2, const float* __restrict__ ab2,
                            const float* __restrict__ bb2, float* __restrict__ out,
                            unsigned* __restrict__ cnt, unsigned* __restrict__ list, int cap) {
  long r = (long)blockIdx.x * 256 + threadIdx.x;
  const float* p0 = part + r * 8;
  const float* p1 = part + (262144L + r) * 8;
  float gl0 = p0[0] + gb2[0], gl1 = p0[1] + gb2[1];
  float fa0 = p0[2] + p1[2] + ab2[0], fa1 = p0[3] + p1[3] + ab2[1];
  float fb0 = p1[4] + bb2[0], fb1 = p1[5] + bb2[1];
  bool m0 = gl0 >= gl1;
  f32x4 o;
  o[0] = m0 ? fa0 : 0.f; o[1] = m0 ? fa1 : 0.f;
  o[2] = m0 ? 0.f : fb0; o[3] = m0 ? 0.f : fb1;
  *(f32x4*)(out + r * 4) = o;
  float diff = gl0 - gl1;
  if (fabsf(diff) < TAU && cap > 0) {
    unsigned u = atomicAdd(cnt, 1u);
    if (u < (unsigned)cap) {
      unsigned* e = list + (size_t)u * 8;
      e[0] = (unsigned)r;
      float* ef = (float*)(e + 4);
      ef[0] = fa0; ef[1] = fa1; ef[2] = fb0; ef[3] = fb1;
    }
  }
}

// ---- fixup: fp64 gate recompute for borderline rows (8 ILP chains) -----------
__global__ void moe_fixup(const float* __restrict__ x,
                          const float* __restrict__ gw1, const float* __restrict__ gb1,
                          const float* __restrict__ gw2, const float* __restrict__ gb2,
                          float* __restrict__ out, const unsigned* __restrict__ cnt,
                          const unsigned* __restrict__ list, int cap) {
  unsigned n = *cnt;
  if (n > (unsigned)cap) n = (unsigned)cap;
  const int l = threadIdx.x & 63;
  const int wid = blockIdx.x * (blockDim.x >> 6) + (threadIdx.x >> 6);
  const int nw = gridDim.x * (blockDim.x >> 6);
  for (unsigned e = wid; e < n; e += nw) {
    const unsigned* ent = list + (size_t)e * 8;
    unsigned row = ent[0];
    const float* ef = (const float*)(ent + 4);
    const float* xr0 = x + (long)row * 256;
    const float* xr1 = x + ((long)row + HALF_ROWS) * 256;
    double a[8] = {0, 0, 0, 0, 0, 0, 0, 0};
#pragma unroll 2
    for (int d = 0; d < 256; d += 8)
#pragma unroll
      for (int q = 0; q < 8; ++q)
        a[q] += (double)xr0[d + q] * (double)gw1[(d + q) * 64 + l];
#pragma unroll 2
    for (int d = 0; d < 256; d += 8)
#pragma unroll
      for (int q = 0; q < 8; ++q)
        a[q] += (double)xr1[d + q] * (double)gw1[(d + 256 + q) * 64 + l];
    double h = ((a[0] + a[1]) + (a[2] + a[3])) + ((a[4] + a[5]) + (a[6] + a[7]))
             + (double)gb1[l];
    h = h > 0.0 ? h : 0.0;
    double t0 = h * (double)gw2[l * 2];
    double t1 = h * (double)gw2[l * 2 + 1];
#pragma unroll
    for (int m = 1; m < 64; m <<= 1) {
      t0 += __shfl_xor(t0, m);
      t1 += __shfl_xor(t1, m);
    }
    if (l == 0) {
      bool m0 = (t0 + (double)gb2[0]) >= (t1 + (double)gb2[1]);
      f32x4 o;
      o[0] = m0 ? ef[0] : 0.f; o[1] = m0 ? ef[1] : 0.f;
      o[2] = m0 ? 0.f : ef[2]; o[3] = m0 ? 0.f : ef[3];
      *(f32x4*)(out + (size_t)row * 4) = o;
    }
  }
}

extern "C" void kernel_launch(void* const* d_in, const int* in_sizes, int n_in,
                              void* d_out, int out_size, void* d_ws, size_t ws_size,
                              hipStream_t stream) {
  const float* x   = (const float*)d_in[0];
  const float* gw1 = (const float*)d_in[1];
  const float* gb1 = (const float*)d_in[2];
  const float* gw2 = (const float*)d_in[3];
  const float* gb2 = (const float*)d_in[4];
  const float* aw1 = (const float*)d_in[5];
  const float* ab1 = (const float*)d_in[6];
  const float* aw2 = (const float*)d_in[7];
  const float* ab2 = (const float*)d_in[8];
  const float* bw1 = (const float*)d_in[9];
  const float* bb1 = (const float*)d_in[10];
  const float* bw2 = (const float*)d_in[11];
  const float* bb2 = (const float*)d_in[12];
  float* out = (float*)d_out;

  unsigned char* ws = (unsigned char*)d_ws;
  unsigned* cnt = (unsigned*)ws;
  unsigned short* Bf = (unsigned short*)(ws + BT_OFF);
  unsigned* list = (unsigned*)(ws + LIST_OFF);
  float* part = (float*)(ws + PART_OFF);
  int cap = (ws_size >= PART_OFF + 2L * 262144 * 32) ? CAP : 0;

  moe_prep<<<320, 512, 0, stream>>>(gw1, aw1, bw1, Bf, cnt);
  moe_main<<<2048, 768, 0, stream>>>(x, Bf, gb1, gw2, ab1, aw2, bb1, bw2, part);
  moe_combine<<<1024, 256, 0, stream>>>(part, gb2, ab2, bb2, out, cnt, list, cap);
  moe_fixup<<<2048, 256, 0, stream>>>(x, gw1, gb1, gw2, gb2, out, cnt, list, cap);
}

// Round 17
// 356.100 us; speedup vs baseline: 1.3750x; 1.3750x over previous
//
#include <hip/hip_runtime.h>
#include <hip/hip_bf16.h>

#define HALF_ROWS 262144
#define TAU 0.04f
#define BT_OFF 1024
#define LIST_OFF 328704              // BT_OFF + 320*512*2

typedef __attribute__((ext_vector_type(8))) short s16x8;
typedef __attribute__((ext_vector_type(4))) float f32x4;
typedef __attribute__((ext_vector_type(16))) float f32x16;

__device__ __forceinline__ unsigned short f2bf(float f) {
  union { float f; unsigned u; } v; v.f = f;
  unsigned r = v.u + 0x7fffu + ((v.u >> 16) & 1u);   // RTNE
  return (unsigned short)(r >> 16);
}

#define GLOAD_LDS16(g, p) \
  __builtin_amdgcn_global_load_lds((const __attribute__((address_space(1))) void*)(g), \
                                   (__attribute__((address_space(3))) void*)(p), 16, 0, 0)

__device__ __forceinline__ s16x8 cvt8(const f32x4& a, const f32x4& b) {
  union { int i[4]; s16x8 v; } u;
  asm("v_cvt_pk_bf16_f32 %0, %1, %2" : "=v"(u.i[0]) : "v"(a[0]), "v"(a[1]));
  asm("v_cvt_pk_bf16_f32 %0, %1, %2" : "=v"(u.i[1]) : "v"(a[2]), "v"(a[3]));
  asm("v_cvt_pk_bf16_f32 %0, %1, %2" : "=v"(u.i[2]) : "v"(b[0]), "v"(b[1]));
  asm("v_cvt_pk_bf16_f32 %0, %1, %2" : "=v"(u.i[3]) : "v"(b[2]), "v"(b[3]));
  return u.v;
}

// ---- prep: W1 -> Bf in 32x32x16 B-fragment order [cb10][kst32][lane64][8] ----
// col = cb*32 + (l&31); k = kst*16 + (l>>5)*8 + j   (R16-verified numerics)
__global__ void moe_prep(const float* __restrict__ gw1, const float* __restrict__ aw1,
                         const float* __restrict__ bw1, unsigned short* __restrict__ Bf,
                         unsigned* __restrict__ cnt) {
  if (blockIdx.x == 0 && threadIdx.x == 0) *cnt = 0u;
  int idx = blockIdx.x * 512 + threadIdx.x;          // 163840
  int j = idx & 7, l = (idx >> 3) & 63, kst = (idx >> 9) & 31, cb = idx >> 14;
  int col = cb * 32 + (l & 31);
  int k = kst * 16 + ((l >> 5) << 3) + j;
  float v;
  if (col < 64)       v = gw1[k * 64 + col];
  else if (col < 192) v = aw1[k * 128 + (col - 64)];
  else                v = bw1[k * 128 + (col - 192)];
  Bf[idx] = f2bf(v);
}

// ---- main: k-halved B (160KB LDS = all 320 cols x k-half), 2 passes ----------
// Pass p: B k-half p in LDS; A = x batch-half p, read ONCE, contiguous 32KB per
// wave-strip. A-loads are the ONLY vmcnt users in the hot loop (B via ds_read =
// lgkmcnt) -> pure descending-FIFO, 8 waves x ~2KB sustained in flight.
// acc[10] (f32x16) persists across passes; full 320-col epilogue is wave-local.
__global__ __launch_bounds__(512, 2) void moe_main(
    const float* __restrict__ x, const unsigned short* __restrict__ Bf,
    const float* __restrict__ gb1, const float* __restrict__ gw2, const float* __restrict__ gb2,
    const float* __restrict__ ab1, const float* __restrict__ aw2, const float* __restrict__ ab2,
    const float* __restrict__ bb1, const float* __restrict__ bw2, const float* __restrict__ bb2,
    float* __restrict__ out, unsigned* __restrict__ cnt, unsigned* __restrict__ list, int cap) {
  __shared__ unsigned short BL[81920];        // 160KB: [cb10][ks16][lane64][8]

  const int tid = threadIdx.x;
  const int w = tid >> 6, l = tid & 63;
  const int lo32 = l & 31, hi2 = l >> 5;
  const long r0 = (long)blockIdx.x * 256 + w * 32;

  // B DMA: 160 x 1KB chunks, 20 per wave; dst = wave-uniform base (+lane*16 by HW)
  auto loadB = [&](int pass) {
#pragma unroll
    for (int i = 0; i < 20; ++i) {
      int c = w * 20 + i;                     // chunk: cb = c>>4, ks = c&15
      const unsigned short* g = Bf + (((size_t)((c >> 4) * 32 + pass * 16 + (c & 15))) << 9) + l * 8;
      GLOAD_LDS16(g, (char*)BL + (size_t)c * 1024);
    }
  };

  f32x16 acc[10];
#pragma unroll
  for (int t = 0; t < 10; ++t)
#pragma unroll
    for (int q = 0; q < 16; ++q) acc[t][q] = 0.f;

#pragma unroll 1
  for (int pass = 0; pass < 2; ++pass) {
    __syncthreads();                          // BL reads from prev pass done
    loadB(pass);
    __syncthreads();                          // DMAs drained (vmcnt(0) + barrier)

    const float* xp = x + ((size_t)(pass ? HALF_ROWS : 0) + r0 + lo32) * 256 + hi2 * 8;
    f32x4 c0 = *(const f32x4*)xp;
    f32x4 c1 = *(const f32x4*)(xp + 4);
    f32x4 c2 = *(const f32x4*)(xp + 16);
    f32x4 c3 = *(const f32x4*)(xp + 20);

#pragma unroll 1
    for (int sk = 0; sk < 8; ++sk) {          // 2 k-steps per iteration
      f32x4 n0, n1, n2, n3;
      if (sk < 7) {                           // prefetch next 2 k-steps (pure-A FIFO)
        const float* np = xp + (sk + 1) * 32;
        n0 = *(const f32x4*)np;
        n1 = *(const f32x4*)(np + 4);
        n2 = *(const f32x4*)(np + 16);
        n3 = *(const f32x4*)(np + 20);
      }
      s16x8 a0 = cvt8(c0, c1);                // waits only its own loads
      s16x8 a1 = cvt8(c2, c3);
#pragma unroll
      for (int t = 0; t < 10; ++t) {
        s16x8 b0 = *(const s16x8*)((const char*)BL + ((size_t)(t * 16 + sk * 2) << 10) + (l << 4));
        acc[t] = __builtin_amdgcn_mfma_f32_32x32x16_bf16(a0, b0, acc[t], 0, 0, 0);
      }
#pragma unroll
      for (int t = 0; t < 10; ++t) {
        s16x8 b1 = *(const s16x8*)((const char*)BL + ((size_t)(t * 16 + sk * 2 + 1) << 10) + (l << 4));
        acc[t] = __builtin_amdgcn_mfma_f32_32x32x16_bf16(a1, b1, acc[t], 0, 0, 0);
      }
      c0 = n0; c1 = n1; c2 = n2; c3 = n3;
    }
  }

  // ---- epilogue: wave-local over all 320 cols --------------------------------
  float pg0[16], pg1[16], pa0[16], pa1[16], pq0[16], pq1[16];
#pragma unroll
  for (int q = 0; q < 16; ++q)
    pg0[q] = pg1[q] = pa0[q] = pa1[q] = pq0[q] = pq1[q] = 0.f;
#pragma unroll
  for (int t = 0; t < 10; ++t) {
    int col = t * 32 + lo32;
    float b1, w0, w1;
    if (t < 2)      { b1 = gb1[col];        w0 = gw2[col * 2];        w1 = gw2[col * 2 + 1]; }
    else if (t < 6) { int c = col - 64;  b1 = ab1[c]; w0 = aw2[c * 2]; w1 = aw2[c * 2 + 1]; }
    else            { int c = col - 192; b1 = bb1[c]; w0 = bw2[c * 2]; w1 = bw2[c * 2 + 1]; }
#pragma unroll
    for (int q = 0; q < 16; ++q) {
      float h = fmaxf(acc[t][q] + b1, 0.f);
      float t0 = h * w0, t1 = h * w1;
      if (t < 2)      { pg0[q] += t0; pg1[q] += t1; }
      else if (t < 6) { pa0[q] += t0; pa1[q] += t1; }
      else            { pq0[q] += t0; pq1[q] += t1; }
    }
  }
#pragma unroll
  for (int m = 1; m < 32; m <<= 1)
#pragma unroll
    for (int q = 0; q < 16; ++q) {
      pg0[q] += __shfl_xor(pg0[q], m); pg1[q] += __shfl_xor(pg1[q], m);
      pa0[q] += __shfl_xor(pa0[q], m); pa1[q] += __shfl_xor(pa1[q], m);
      pq0[q] += __shfl_xor(pq0[q], m); pq1[q] += __shfl_xor(pq1[q], m);
    }
  if (lo32 == 0) {
#pragma unroll
    for (int q = 0; q < 16; ++q) {
      long grow = r0 + (q & 3) + 8 * (q >> 2) + 4 * hi2;   // C/D row map (m74/m101)
      float gl0 = pg0[q] + gb2[0], gl1 = pg1[q] + gb2[1];
      float fa0 = pa0[q] + ab2[0], fa1 = pa1[q] + ab2[1];
      float fb0 = pq0[q] + bb2[0], fb1 = pq1[q] + bb2[1];
      bool m0 = gl0 >= gl1;
      f32x4 o;
      o[0] = m0 ? fa0 : 0.f; o[1] = m0 ? fa1 : 0.f;
      o[2] = m0 ? 0.f : fb0; o[3] = m0 ? 0.f : fb1;
      *(f32x4*)(out + grow * 4) = o;
      float diff = gl0 - gl1;
      if (fabsf(diff) < TAU && cap > 0) {
        unsigned u = atomicAdd(cnt, 1u);
        if (u < (unsigned)cap) {
          unsigned* e = list + (size_t)u * 8;
          e[0] = (unsigned)grow;
          float* ef = (float*)(e + 4);
          ef[0] = fa0; ef[1] = fa1; ef[2] = fb0; ef[3] = fb1;
        }
      }
    }
  }
}

// ---- fixup: fp64 gate recompute for borderline rows (8 ILP chains) -----------
__global__ void moe_fixup(const float* __restrict__ x,
                          const float* __restrict__ gw1, const float* __restrict__ gb1,
                          const float* __restrict__ gw2, const float* __restrict__ gb2,
                          float* __restrict__ out, const unsigned* __restrict__ cnt,
                          const unsigned* __restrict__ list, int cap) {
  unsigned n = *cnt;
  if (n > (unsigned)cap) n = (unsigned)cap;
  const int l = threadIdx.x & 63;
  const int wid = blockIdx.x * (blockDim.x >> 6) + (threadIdx.x >> 6);
  const int nw = gridDim.x * (blockDim.x >> 6);
  for (unsigned e = wid; e < n; e += nw) {
    const unsigned* ent = list + (size_t)e * 8;
    unsigned row = ent[0];
    const float* ef = (const float*)(ent + 4);
    const float* xr0 = x + (long)row * 256;
    const float* xr1 = x + ((long)row + HALF_ROWS) * 256;
    double a[8] = {0, 0, 0, 0, 0, 0, 0, 0};
#pragma unroll 2
    for (int d = 0; d < 256; d += 8)
#pragma unroll
      for (int q = 0; q < 8; ++q)
        a[q] += (double)xr0[d + q] * (double)gw1[(d + q) * 64 + l];
#pragma unroll 2
    for (int d = 0; d < 256; d += 8)
#pragma unroll
      for (int q = 0; q < 8; ++q)
        a[q] += (double)xr1[d + q] * (double)gw1[(d + 256 + q) * 64 + l];
    double h = ((a[0] + a[1]) + (a[2] + a[3])) + ((a[4] + a[5]) + (a[6] + a[7]))
             + (double)gb1[l];
    h = h > 0.0 ? h : 0.0;
    double t0 = h * (double)gw2[l * 2];
    double t1 = h * (double)gw2[l * 2 + 1];
#pragma unroll
    for (int m = 1; m < 64; m <<= 1) {
      t0 += __shfl_xor(t0, m);
      t1 += __shfl_xor(t1, m);
    }
    if (l == 0) {
      bool m0 = (t0 + (double)gb2[0]) >= (t1 + (double)gb2[1]);
      f32x4 o;
      o[0] = m0 ? ef[0] : 0.f; o[1] = m0 ? ef[1] : 0.f;
      o[2] = m0 ? 0.f : ef[2]; o[3] = m0 ? 0.f : ef[3];
      *(f32x4*)(out + (size_t)row * 4) = o;
    }
  }
}

extern "C" void kernel_launch(void* const* d_in, const int* in_sizes, int n_in,
                              void* d_out, int out_size, void* d_ws, size_t ws_size,
                              hipStream_t stream) {
  const float* x   = (const float*)d_in[0];
  const float* gw1 = (const float*)d_in[1];
  const float* gb1 = (const float*)d_in[2];
  const float* gw2 = (const float*)d_in[3];
  const float* gb2 = (const float*)d_in[4];
  const float* aw1 = (const float*)d_in[5];
  const float* ab1 = (const float*)d_in[6];
  const float* aw2 = (const float*)d_in[7];
  const float* ab2 = (const float*)d_in[8];
  const float* bw1 = (const float*)d_in[9];
  const float* bb1 = (const float*)d_in[10];
  const float* bw2 = (const float*)d_in[11];
  const float* bb2 = (const float*)d_in[12];
  float* out = (float*)d_out;

  unsigned char* ws = (unsigned char*)d_ws;
  unsigned* cnt = (unsigned*)ws;
  unsigned short* Bf = (unsigned short*)(ws + BT_OFF);
  unsigned* list = (unsigned*)(ws + LIST_OFF);
  long cap_l = ((long)ws_size - (long)LIST_OFF) / 32;
  int cap = cap_l < 0 ? 0 : (cap_l > 262144 ? 262144 : (int)cap_l);

  moe_prep<<<320, 512, 0, stream>>>(gw1, aw1, bw1, Bf, cnt);
  moe_main<<<1024, 512, 0, stream>>>(x, Bf, gb1, gw2, gb2, ab1, aw2, ab2,
                                     bb1, bw2, bb2, out, cnt, list, cap);
  moe_fixup<<<2048, 256, 0, stream>>>(x, gw1, gb1, gw2, gb2, out, cnt, list, cap);
}

// Round 18
// 289.041 us; speedup vs baseline: 1.6940x; 1.2320x over previous
//
#include <hip/hip_runtime.h>
#include <hip/hip_bf16.h>

#define HALF_ROWS 262144
#define TAU 0.04f
#define BT_OFF 1024
#define LIST_OFF (BT_OFF + 320 * 512 * 2)   // 1024 + 327680
#define NC 16

typedef __attribute__((ext_vector_type(8))) short s16x8;
typedef __attribute__((ext_vector_type(4))) float f32x4;

__device__ __forceinline__ unsigned short f2bf(float f) {
  union { float f; unsigned u; } v; v.f = f;
  unsigned r = v.u + 0x7fffu + ((v.u >> 16) & 1u);   // RTNE
  return (unsigned short)(r >> 16);
}

#define GLOAD_LDS16(g, p) \
  __builtin_amdgcn_global_load_lds((const __attribute__((address_space(1))) void*)(g), \
                                   (__attribute__((address_space(3))) void*)(p), 16, 0, 0)

__device__ __forceinline__ s16x8 cvt8(const f32x4& a, const f32x4& b) {
  union { int i[4]; s16x8 v; } u;
  asm("v_cvt_pk_bf16_f32 %0, %1, %2" : "=v"(u.i[0]) : "v"(a[0]), "v"(a[1]));
  asm("v_cvt_pk_bf16_f32 %0, %1, %2" : "=v"(u.i[1]) : "v"(a[2]), "v"(a[3]));
  asm("v_cvt_pk_bf16_f32 %0, %1, %2" : "=v"(u.i[2]) : "v"(b[0]), "v"(b[1]));
  asm("v_cvt_pk_bf16_f32 %0, %1, %2" : "=v"(u.i[3]) : "v"(b[2]), "v"(b[3]));
  return u.v;
}

// ---- prep: W1 -> Bf in MFMA B-fragment order [cb20][ks16][lane64][8] ---------
__global__ void moe_prep(const float* __restrict__ gw1, const float* __restrict__ aw1,
                         const float* __restrict__ bw1, unsigned short* __restrict__ Bf,
                         unsigned* __restrict__ cnt) {
  if (blockIdx.x == 0 && threadIdx.x == 0) *cnt = 0u;
  int idx = blockIdx.x * 512 + threadIdx.x;          // 320*512 = 163840
  int j = idx & 7, l = (idx >> 3) & 63, ks = (idx >> 9) & 15, cb = idx >> 13;
  int col = cb * 16 + (l & 15);
  int k = ks * 32 + ((l >> 4) << 3) + j;
  float v;
  if (col < 64)       v = gw1[k * 64 + col];
  else if (col < 192) v = aw1[k * 128 + (col - 64)];
  else                v = bw1[k * 128 + (col - 192)];
  Bf[idx] = f2bf(v);
}

// ---- main: R13 producer/consumer + XCD swizzle (T1) + consumer setprio (T5) --
// 12 waves: w0-3 producers (A reg-staged 2-deep, B DMA 3-ring, vmcnt(9) steady,
// never 0 till tail), w4-11 consumers (16 rows each, LDS->MFMA only).
// One barrier per chunk. BM=128, BK=32, 16 chunks.
__global__ __launch_bounds__(768, 3) void moe_main(
    const float* __restrict__ x, const unsigned short* __restrict__ Bf,
    const float* __restrict__ gb1, const float* __restrict__ gw2, const float* __restrict__ gb2,
    const float* __restrict__ ab1, const float* __restrict__ aw2, const float* __restrict__ ab2,
    const float* __restrict__ bb1, const float* __restrict__ bw2, const float* __restrict__ bb2,
    float* __restrict__ out, unsigned* __restrict__ cnt, unsigned* __restrict__ list, int cap) {
  __shared__ char Asl[2][8192];               // A ring: [grp8][lane64][16B]
  __shared__ char Bsl[3][20480];              // B ring: [cb20][lane64][16B]

  const int tid = threadIdx.x;
  const int w = tid >> 6, l = tid & 63;
  const int lo = l & 15, hi = l >> 4;
  // T1: bijective XCD swizzle; nwg = 2048 = 8 x 256, each XCD gets a
  // contiguous 256-block (32768-row) range -> x-panel L2/L3 locality.
  const int bid = ((blockIdx.x & 7) << 8) | (blockIdx.x >> 3);
  const long br = (long)bid * 128;

  if (w < 4) {
    // ======================= PRODUCER =======================
    const float* apg0 = x + (br + w * 32 + lo) * 256 + hi * 8;   // group w*2
    const unsigned short* bsrc = Bf + l * 8;
    const int cb0 = w * 5;

    f32x4 sA[4], sB[4];
#define ISSUE_A(KC, S)                                                             \
    {                                                                              \
      const float* pb = ((KC) < 8) ? apg0 : (apg0 + (long)HALF_ROWS * 256);        \
      const float* p0 = pb + ((KC) & 7) * 32;                                      \
      const float* p1 = p0 + 16 * 256;                                             \
      asm volatile("global_load_dwordx4 %0, %1, off" : "=&v"(S[0]) : "v"(p0));     \
      asm volatile("global_load_dwordx4 %0, %1, off" : "=&v"(S[1]) : "v"(p0 + 4)); \
      asm volatile("global_load_dwordx4 %0, %1, off" : "=&v"(S[2]) : "v"(p1));     \
      asm volatile("global_load_dwordx4 %0, %1, off" : "=&v"(S[3]) : "v"(p1 + 4)); \
    }
    auto issueB = [&](int kc) {
      char* dst = Bsl[((unsigned)kc) % 3u] + cb0 * 1024;
#pragma unroll
      for (int s = 0; s < 5; ++s)
        GLOAD_LDS16(bsrc + (((size_t)((cb0 + s) * 16 + kc)) << 9), dst + s * 1024);
    };
#define COMMIT_A(KC, S)                                                            \
    {                                                                              \
      char* dst = Asl[(KC) & 1];                                                   \
      s16x8 v0 = cvt8(S[0], S[1]);                                                 \
      s16x8 v1 = cvt8(S[2], S[3]);                                                 \
      *(s16x8*)(dst + (w * 2) * 1024 + l * 16) = v0;                               \
      *(s16x8*)(dst + (w * 2 + 1) * 1024 + l * 16) = v1;                           \
    }
#define PWAIT(N) asm volatile("s_waitcnt vmcnt(" #N ")" ::: "memory"); \
                 __builtin_amdgcn_sched_barrier(0)
#define PBAR()   asm volatile("s_waitcnt lgkmcnt(0)" ::: "memory");    \
                 __builtin_amdgcn_s_barrier()

    ISSUE_A(0, sA) issueB(0);
    ISSUE_A(1, sB) issueB(1);
    PWAIT(9);                         // A0+B0 landed (A1+B1 remain)
    COMMIT_A(0, sA)
    PBAR();                           // barrier #1: chunk0 ready

#pragma unroll 1
    for (int kc = 0; kc < 14; kc += 2) {
      ISSUE_A(kc + 2, sA) issueB(kc + 2);
      PWAIT(9);
      COMMIT_A(kc + 1, sB)
      PBAR();
      if (kc + 3 < NC) {
        ISSUE_A(kc + 3, sB) issueB(kc + 3);
        PWAIT(9);
      } else {
        PWAIT(0);
      }
      COMMIT_A(kc + 2, sA)
      PBAR();
    }
    PWAIT(0);
    COMMIT_A(15, sB)
    PBAR();                           // barrier #16: chunk15 ready
  } else {
    // ======================= CONSUMER =======================
    const int cw = w - 4;             // 0..7, owns rows br + cw*16 ..+15
    f32x4 acc[20];
#pragma unroll
    for (int ct = 0; ct < 20; ++ct) acc[ct] = (f32x4){0.f, 0.f, 0.f, 0.f};

#pragma unroll 1
    for (int kc = 0; kc < NC; ++kc) {
      __builtin_amdgcn_s_barrier();   // barrier #kc+1: chunk kc ready
      asm volatile("" ::: "memory");
      const char* ab = Asl[kc & 1];
      const char* bb = Bsl[((unsigned)kc) % 3u];
      s16x8 af = *(const s16x8*)(ab + cw * 1024 + l * 16);
      __builtin_amdgcn_s_setprio(1);  // T5: favor MFMA-entering consumer waves
#pragma unroll
      for (int ct = 0; ct < 20; ++ct) {
        s16x8 bf = *(const s16x8*)(bb + ct * 1024 + l * 16);
        acc[ct] = __builtin_amdgcn_mfma_f32_16x16x32_bf16(af, bf, acc[ct], 0, 0, 0);
      }
      __builtin_amdgcn_s_setprio(0);
    }

    // ---- epilogue: wave-local, 16 rows x all 320 cols ----
    float pg0[4] = {0,0,0,0}, pg1[4] = {0,0,0,0};
    float pa0[4] = {0,0,0,0}, pa1[4] = {0,0,0,0};
    float pq0[4] = {0,0,0,0}, pq1[4] = {0,0,0,0};
#pragma unroll
    for (int ct = 0; ct < 20; ++ct) {
      int col = ct * 16 + lo;
      float b1, w0, w1;
      if (ct < 4)       { b1 = gb1[col];        w0 = gw2[col * 2];        w1 = gw2[col * 2 + 1]; }
      else if (ct < 12) { int c = col - 64;  b1 = ab1[c]; w0 = aw2[c * 2]; w1 = aw2[c * 2 + 1]; }
      else              { int c = col - 192; b1 = bb1[c]; w0 = bw2[c * 2]; w1 = bw2[c * 2 + 1]; }
#pragma unroll
      for (int j = 0; j < 4; ++j) {
        float h = fmaxf(acc[ct][j] + b1, 0.f);
        float t0 = h * w0, t1 = h * w1;
        if (ct < 4)       { pg0[j] += t0; pg1[j] += t1; }
        else if (ct < 12) { pa0[j] += t0; pa1[j] += t1; }
        else              { pq0[j] += t0; pq1[j] += t1; }
      }
    }
#pragma unroll
    for (int m = 1; m < 16; m <<= 1)
#pragma unroll
      for (int j = 0; j < 4; ++j) {
        pg0[j] += __shfl_xor(pg0[j], m); pg1[j] += __shfl_xor(pg1[j], m);
        pa0[j] += __shfl_xor(pa0[j], m); pa1[j] += __shfl_xor(pa1[j], m);
        pq0[j] += __shfl_xor(pq0[j], m); pq1[j] += __shfl_xor(pq1[j], m);
      }
    if (lo == 0) {
#pragma unroll
      for (int j = 0; j < 4; ++j) {
        long grow = br + cw * 16 + hi * 4 + j;
        float gl0 = pg0[j] + gb2[0], gl1 = pg1[j] + gb2[1];
        float fa0 = pa0[j] + ab2[0], fa1 = pa1[j] + ab2[1];
        float fb0 = pq0[j] + bb2[0], fb1 = pq1[j] + bb2[1];
        bool m0 = gl0 >= gl1;
        f32x4 o;
        o[0] = m0 ? fa0 : 0.f; o[1] = m0 ? fa1 : 0.f;
        o[2] = m0 ? 0.f : fb0; o[3] = m0 ? 0.f : fb1;
        *(f32x4*)(out + grow * 4) = o;
        float diff = gl0 - gl1;
        if (fabsf(diff) < TAU && cap > 0) {
          unsigned u = atomicAdd(cnt, 1u);
          if (u < (unsigned)cap) {
            unsigned* e = list + (size_t)u * 8;
            e[0] = (unsigned)grow;
            float* ef = (float*)(e + 4);
            ef[0] = fa0; ef[1] = fa1; ef[2] = fb0; ef[3] = fb1;
          }
        }
      }
    }
  }
}

// ---- fixup: fp64 gate recompute for borderline rows (8 ILP chains) -----------
__global__ void moe_fixup(const float* __restrict__ x,
                          const float* __restrict__ gw1, const float* __restrict__ gb1,
                          const float* __restrict__ gw2, const float* __restrict__ gb2,
                          float* __restrict__ out, const unsigned* __restrict__ cnt,
                          const unsigned* __restrict__ list, int cap) {
  unsigned n = *cnt;
  if (n > (unsigned)cap) n = (unsigned)cap;
  const int l = threadIdx.x & 63;
  const int wid = blockIdx.x * (blockDim.x >> 6) + (threadIdx.x >> 6);
  const int nw = gridDim.x * (blockDim.x >> 6);
  for (unsigned e = wid; e < n; e += nw) {
    const unsigned* ent = list + (size_t)e * 8;
    unsigned row = ent[0];
    const float* ef = (const float*)(ent + 4);
    const float* xr0 = x + (long)row * 256;
    const float* xr1 = x + ((long)row + HALF_ROWS) * 256;
    double a[8] = {0, 0, 0, 0, 0, 0, 0, 0};
#pragma unroll 2
    for (int d = 0; d < 256; d += 8)
#pragma unroll
      for (int q = 0; q < 8; ++q)
        a[q] += (double)xr0[d + q] * (double)gw1[(d + q) * 64 + l];
#pragma unroll 2
    for (int d = 0; d < 256; d += 8)
#pragma unroll
      for (int q = 0; q < 8; ++q)
        a[q] += (double)xr1[d + q] * (double)gw1[(d + 256 + q) * 64 + l];
    double h = ((a[0] + a[1]) + (a[2] + a[3])) + ((a[4] + a[5]) + (a[6] + a[7]))
             + (double)gb1[l];
    h = h > 0.0 ? h : 0.0;
    double t0 = h * (double)gw2[l * 2];
    double t1 = h * (double)gw2[l * 2 + 1];
#pragma unroll
    for (int m = 1; m < 64; m <<= 1) {
      t0 += __shfl_xor(t0, m);
      t1 += __shfl_xor(t1, m);
    }
    if (l == 0) {
      bool m0 = (t0 + (double)gb2[0]) >= (t1 + (double)gb2[1]);
      f32x4 o;
      o[0] = m0 ? ef[0] : 0.f; o[1] = m0 ? ef[1] : 0.f;
      o[2] = m0 ? 0.f : ef[2]; o[3] = m0 ? 0.f : ef[3];
      *(f32x4*)(out + (size_t)row * 4) = o;
    }
  }
}

extern "C" void kernel_launch(void* const* d_in, const int* in_sizes, int n_in,
                              void* d_out, int out_size, void* d_ws, size_t ws_size,
                              hipStream_t stream) {
  const float* x   = (const float*)d_in[0];
  const float* gw1 = (const float*)d_in[1];
  const float* gb1 = (const float*)d_in[2];
  const float* gw2 = (const float*)d_in[3];
  const float* gb2 = (const float*)d_in[4];
  const float* aw1 = (const float*)d_in[5];
  const float* ab1 = (const float*)d_in[6];
  const float* aw2 = (const float*)d_in[7];
  const float* ab2 = (const float*)d_in[8];
  const float* bw1 = (const float*)d_in[9];
  const float* bb1 = (const float*)d_in[10];
  const float* bw2 = (const float*)d_in[11];
  const float* bb2 = (const float*)d_in[12];
  float* out = (float*)d_out;

  unsigned char* ws = (unsigned char*)d_ws;
  unsigned* cnt = (unsigned*)ws;
  unsigned short* Bf = (unsigned short*)(ws + BT_OFF);
  unsigned* list = (unsigned*)(ws + LIST_OFF);
  long cap_l = ((long)ws_size - (long)LIST_OFF) / 32;
  int cap = cap_l < 0 ? 0 : (cap_l > 262144 ? 262144 : (int)cap_l);

  moe_prep<<<320, 512, 0, stream>>>(gw1, aw1, bw1, Bf, cnt);
  moe_main<<<2048, 768, 0, stream>>>(x, Bf, gb1, gw2, gb2, ab1, aw2, ab2,
                                     bb1, bw2, bb2, out, cnt, list, cap);
  moe_fixup<<<2048, 256, 0, stream>>>(x, gw1, gb1, gw2, gb2, out, cnt, list, cap);
}